// Round 11
// baseline (147.361 us; speedup 1.0000x reference)
//
#include <hip/hip_runtime.h>
#include <math.h>

#define NQ 10
#define NL 4

typedef float v2f __attribute__((ext_vector_type(2)));

// 40 gate matrices (8 floats each), computed once per launch by prep_gates.
// Lives in the module's device .bss — no dependence on d_ws.
__device__ float g_gates[NL * NQ * 8];

// ---------- cross-lane primitives (all R8/R10-verified) ----------
template<int CTRL>
__device__ __forceinline__ float dppx(float v) {  // DPP (VALU pipe)
  return __int_as_float(__builtin_amdgcn_update_dpp(0, __float_as_int(v), CTRL, 0xF, 0xF, true));
}
template<int OFF>
__device__ __forceinline__ float swzx(float v) {  // ds_swizzle (DS pipe)
  return __int_as_float(__builtin_amdgcn_ds_swizzle(__float_as_int(v), OFF));
}
__device__ __forceinline__ void pl16swap(float &a, float &b) {  // VALU
  asm("v_permlane16_swap_b32 %0, %1" : "+v"(a), "+v"(b));
}
__device__ __forceinline__ void pl32swap(float &a, float &b) {  // VALU
  asm("v_permlane32_swap_b32 %0, %1" : "+v"(a), "+v"(b));
}

// partner fetch for lane-bit LB in {0,1,2,3}: xor1/2 DPP (VALU), xor4/8 swizzle (DS)
template<int LB>
__device__ __forceinline__ float part(float v) {
  if constexpr (LB == 0) return dppx<0xB1>(v);
  else if constexpr (LB == 1) return dppx<0x4E>(v);
  else if constexpr (LB == 2) return swzx<0x101F>(v);
  else return swzx<0x201F>(v);
}

// ---------- packed complex arithmetic (VOP3P, R4-verified) ----------
__device__ __forceinline__ v2f cmul(v2f u, v2f a) {
  v2f d;
  asm("v_pk_mul_f32 %0, %1, %2 op_sel_hi:[0,1]\n\t"
      "v_pk_fma_f32 %0, %1, %2, %0 op_sel:[1,1,0] op_sel_hi:[1,0,1] neg_lo:[0,1,0]"
      : "=&v"(d) : "v"(u), "v"(a));
  return d;
}
__device__ __forceinline__ void cfma(v2f &d, v2f u, v2f a) {
  asm("v_pk_fma_f32 %0, %1, %2, %0 op_sel_hi:[0,1,1]\n\t"
      "v_pk_fma_f32 %0, %1, %2, %0 op_sel:[1,1,0] op_sel_hi:[1,0,1] neg_lo:[0,1,0]"
      : "+v"(d) : "v"(u), "v"(a));
}

// ---------- gates (R8-verified structure) ----------
template<int RB>
__device__ __forceinline__ void gate_rbit(v2f a[16], v2f u00, v2f u01, v2f u10, v2f u11) {
#pragma unroll
  for (int r0 = 0; r0 < 16; ++r0) {
    if ((r0 >> RB) & 1) continue;
    const int r1 = r0 | (1 << RB);
    const v2f a0 = a[r0], a1 = a[r1];
    v2f n0 = cmul(u00, a0); cfma(n0, u01, a1);
    v2f n1 = cmul(u10, a0); cfma(n1, u11, a1);
    a[r0] = n0;
    a[r1] = n1;
  }
}

template<int LB>
__device__ __forceinline__ void gate_part(v2f a[16], v2f cS, v2f cP) {
#pragma unroll
  for (int h = 0; h < 4; ++h) {
    v2f p[4];
#pragma unroll
    for (int k = 0; k < 4; ++k) {
      const int r = h * 4 + k;
      p[k].x = part<LB>(a[r].x);
      p[k].y = part<LB>(a[r].y);
    }
#pragma unroll
    for (int k = 0; k < 4; ++k) {
      const int r = h * 4 + k;
      v2f n = cmul(cS, a[r]); cfma(n, cP, p[k]);
      a[r] = n;
    }
  }
}

// bit4 (IS32=false) / bit5 (IS32=true) via permlane swaps (VALU only; R2/R8-verified)
template<bool IS32>
__device__ __forceinline__ void gate_swap(v2f a[16], v2f cL, v2f cH) {
#pragma unroll
  for (int r = 0; r < 16; ++r) {
    float lx = a[r].x, hx = a[r].x;
    float ly = a[r].y, hy = a[r].y;
    if constexpr (IS32) { pl32swap(lx, hx); pl32swap(ly, hy); }
    else                { pl16swap(lx, hx); pl16swap(ly, hy); }
    v2f lo, hi;
    lo.x = lx; lo.y = ly;
    hi.x = hx; hi.y = hy;
    v2f n = cmul(cL, lo); cfma(n, cH, hi);
    a[r] = n;
  }
}

// ---------- whole CNOT ring as ONE linear permutation (HW-verified R2-R10):
// dst[r'][lane'] = src[gray4(r') ^ ((lane'&1)*12)][(lane'^(lane'>>1)) ^ ((r'&1)<<5)]
__device__ __forceinline__ void ring_comp(v2f a[16], int addr0, int addr1, bool odd) {
  float B[16];
#pragma unroll
  for (int g = 0; g < 16; ++g) {
    const int par = ((g ^ (g >> 1) ^ (g >> 2) ^ (g >> 3)) & 1);
    B[g] = __int_as_float(__builtin_amdgcn_ds_bpermute(par ? addr1 : addr0,
                                                       __float_as_int(a[g].x)));
  }
#pragma unroll
  for (int r = 0; r < 16; ++r) {
    const int g = (r ^ (r >> 1));
    a[r].x = odd ? B[g ^ 12] : B[g];
  }
#pragma unroll
  for (int g = 0; g < 16; ++g) {
    const int par = ((g ^ (g >> 1) ^ (g >> 2) ^ (g >> 3)) & 1);
    B[g] = __int_as_float(__builtin_amdgcn_ds_bpermute(par ? addr1 : addr0,
                                                       __float_as_int(a[g].y)));
  }
#pragma unroll
  for (int r = 0; r < 16; ++r) {
    const int g = (r ^ (r >> 1));
    a[r].y = odd ? B[g ^ 12] : B[g];
  }
}

// full 64-lane sum (R8-verified stages)
__device__ __forceinline__ float wsum(float v) {
  v += dppx<0xB1>(v);
  v += dppx<0x4E>(v);
  v += swzx<0x101F>(v);
  v += swzx<0x201F>(v);
  { float a = v, b = v; pl16swap(a, b); v = a + b; }
  { float a = v, b = v; pl32swap(a, b); v = a + b; }
  return v;
}

// product-state encoding (R4-verified structure, native trig)
__device__ __forceinline__ void encode(const float* __restrict__ xb, int lane, v2f a[16]) {
  float lfac;
  {
    float c, s, h;
    h = 0.5f * xb[9]; s = __sinf(h); c = __cosf(h); lfac  = ((lane >> 0) & 1) ? s : c;
    h = 0.5f * xb[8]; s = __sinf(h); c = __cosf(h); lfac *= ((lane >> 1) & 1) ? s : c;
    h = 0.5f * xb[7]; s = __sinf(h); c = __cosf(h); lfac *= ((lane >> 2) & 1) ? s : c;
    h = 0.5f * xb[6]; s = __sinf(h); c = __cosf(h); lfac *= ((lane >> 3) & 1) ? s : c;
    h = 0.5f * xb[5]; s = __sinf(h); c = __cosf(h); lfac *= ((lane >> 4) & 1) ? s : c;
    h = 0.5f * xb[4]; s = __sinf(h); c = __cosf(h); lfac *= ((lane >> 5) & 1) ? s : c;
  }
  const float h0 = 0.5f * xb[0], h1 = 0.5f * xb[1], h2 = 0.5f * xb[2], h3 = 0.5f * xb[3];
  const float s0 = __sinf(h0), c0 = __cosf(h0);
  const float s1 = __sinf(h1), c1 = __cosf(h1);
  const float s2 = __sinf(h2), c2 = __cosf(h2);
  const float s3 = __sinf(h3), c3 = __cosf(h3);
#pragma unroll
  for (int r = 0; r < 16; ++r) {
    float f = lfac;                     // r bit rb <-> qubit 3-rb
    f *= ((r >> 0) & 1) ? s3 : c3;
    f *= ((r >> 1) & 1) ? s2 : c2;
    f *= ((r >> 2) & 1) ? s1 : c1;
    f *= ((r >> 3) & 1) ? s0 : c0;
    a[r].x = f;
    a[r].y = 0.f;
  }
}

// ---------- setup kernel ----------
__global__ void prep_gates(const float* __restrict__ w) {
  const int t = threadIdx.x;
  if (t < NL * NQ) {
    const float phi = w[t * 3 + 0];
    const float th  = w[t * 3 + 1];
    const float om  = w[t * 3 + 2];
    const float c  = __cosf(0.5f * th),          s  = __sinf(0.5f * th);
    const float cp = __cosf(-0.5f * (phi + om)), sp = __sinf(-0.5f * (phi + om));
    const float cm = __cosf(0.5f * (phi - om)),  sm = __sinf(0.5f * (phi - om));
    float* g = g_gates + t * 8;
    g[0] = cp * c;  g[1] = sp * c;    // u00
    g[2] = -cm * s; g[3] = -sm * s;   // u01
    g[4] = cm * s;  g[5] = -sm * s;   // u10
    g[6] = cp * c;  g[7] = -sp * c;   // u11
  }
}

// ONE WAVE PER BLOCK: finest workgroup granularity so the CP can pack CUs
// to the wave limit instead of 4-wave (256-thread) block granularity.
__global__ __launch_bounds__(64) void qsim_kernel(const float* __restrict__ x,
                                                  float* __restrict__ out,
                                                  int batch) {
  const int samp = (int)blockIdx.x;
  const int lane = threadIdx.x;   // 0..63
  if (samp >= batch) return;

  const int addr0 = 4 * (lane ^ (lane >> 1));
  const int addr1 = addr0 ^ 128;
  const bool lodd = (lane & 1);

  v2f a[16];
  encode(x + samp * NQ, lane, a);

  // ---- layers; gate coefficients are wave-uniform loads from g_gates
#pragma unroll
  for (int l = 0; l < NL; ++l) {
    const float* gl = g_gates + l * NQ * 8;

    // qubits 0..3: register-bit gates (fully uniform coefficients)
#pragma unroll
    for (int q = 0; q < 4; ++q) {
      const float* g = gl + q * 8;
      const v2f u00 = {g[0], g[1]}, u01 = {g[2], g[3]};
      const v2f u10 = {g[4], g[5]}, u11 = {g[6], g[7]};
      if (q == 0)      gate_rbit<3>(a, u00, u01, u10, u11);
      else if (q == 1) gate_rbit<2>(a, u00, u01, u10, u11);
      else if (q == 2) gate_rbit<1>(a, u00, u01, u10, u11);
      else             gate_rbit<0>(a, u00, u01, u10, u11);
    }
    // qubit 4 (lane bit 5): permlane32_swap gate (VALU)
    {
      const float* g = gl + 4 * 8;
      const bool hb = (lane >> 5) & 1;
      const v2f u00 = {g[0], g[1]}, u01 = {g[2], g[3]};
      const v2f u10 = {g[4], g[5]}, u11 = {g[6], g[7]};
      const v2f cL = hb ? u10 : u00;
      const v2f cH = hb ? u11 : u01;
      gate_swap<true>(a, cL, cH);
    }
    // qubit 5 (lane bit 4): permlane16_swap gate (VALU)
    {
      const float* g = gl + 5 * 8;
      const bool hb = (lane >> 4) & 1;
      const v2f u00 = {g[0], g[1]}, u01 = {g[2], g[3]};
      const v2f u10 = {g[4], g[5]}, u11 = {g[6], g[7]};
      const v2f cL = hb ? u10 : u00;
      const v2f cH = hb ? u11 : u01;
      gate_swap<false>(a, cL, cH);
    }
    // qubits 6..9 (lane bits 3..0): partner gates
#pragma unroll
    for (int q = 6; q < 10; ++q) {
      const float* g = gl + q * 8;
      const bool hb = (lane >> (9 - q)) & 1;
      const v2f u00 = {g[0], g[1]}, u01 = {g[2], g[3]};
      const v2f u10 = {g[4], g[5]}, u11 = {g[6], g[7]};
      const v2f cS = hb ? u11 : u00;
      const v2f cP = hb ? u10 : u01;
      if (q == 6)      gate_part<3>(a, cS, cP);
      else if (q == 7) gate_part<2>(a, cS, cP);
      else if (q == 8) gate_part<1>(a, cS, cP);
      else             gate_part<0>(a, cS, cP);
    }

    // entire CNOT ring as one permutation
    ring_comp(a, addr0, addr1, lodd);
  }

  // ---- measurement
  float p[16];
#pragma unroll
  for (int r = 0; r < 16; ++r) p[r] = a[r].x * a[r].x + a[r].y * a[r].y;

  // z0..3 (register-bit qubits): per-lane signed partials + plain wsum
  float z03[4];
#pragma unroll
  for (int q = 0; q < 4; ++q) {
    const int rb = 3 - q;
    float acc = 0.f;
#pragma unroll
    for (int r = 0; r < 16; ++r) acc += ((r >> rb) & 1) ? -p[r] : p[r];
    z03[q] = wsum(acc);
  }

  // z4..9 (lane-bit qubits): ONE signed 6-stage Walsh-Hadamard butterfly over P.
  // After it, lane L=1<<lb holds sum_M (-1)^{bit lb of M} P(M) = z[9-lb].
  float P = 0.f;
#pragma unroll
  for (int r = 0; r < 16; ++r) P += p[r];
  const float sg0 = (lane & 1)  ? -1.f : 1.f;
  const float sg1 = (lane & 2)  ? -1.f : 1.f;
  const float sg2 = (lane & 4)  ? -1.f : 1.f;
  const float sg3 = (lane & 8)  ? -1.f : 1.f;
  const float sg4 = (lane & 16) ? -1.f : 1.f;
  const float sg5 = (lane & 32) ? -1.f : 1.f;
  float v = P;
  v = __builtin_fmaf(sg0, v, dppx<0xB1>(v));    // bit0
  v = __builtin_fmaf(sg1, v, dppx<0x4E>(v));    // bit1
  v = __builtin_fmaf(sg2, v, swzx<0x101F>(v));  // bit2 (DS)
  v = __builtin_fmaf(sg3, v, swzx<0x201F>(v));  // bit3 (DS)
  { float xx = v, yy = v; pl16swap(xx, yy); v = __builtin_fmaf(sg4, yy, xx); }  // bit4
  { float xx = v, yy = v; pl32swap(xx, yy); v = __builtin_fmaf(sg5, yy, xx); }  // bit5

  if (lane == 0) {
    out[samp * NQ + 0] = z03[0];
    out[samp * NQ + 1] = z03[1];
    out[samp * NQ + 2] = z03[2];
    out[samp * NQ + 3] = z03[3];
  } else if ((lane & (lane - 1)) == 0) {      // lane in {1,2,4,8,16,32}
    const int lb = __ffs(lane) - 1;           // 0..5
    out[samp * NQ + (9 - lb)] = v;            // q = 9 - lb in 4..9
  }
}

extern "C" void kernel_launch(void* const* d_in, const int* in_sizes, int n_in,
                              void* d_out, int out_size, void* d_ws, size_t ws_size,
                              hipStream_t stream) {
  const float* x = (const float*)d_in[0];
  const float* w = (const float*)d_in[1];
  float* out = (float*)d_out;
  const int batch = in_sizes[0] / NQ;

  hipLaunchKernelGGL(prep_gates, dim3(1), dim3(64), 0, stream, w);
  hipLaunchKernelGGL(qsim_kernel, dim3(batch), dim3(64), 0, stream, x, out, batch);
}

// Round 14
// 132.180 us; speedup vs baseline: 1.1148x; 1.1148x over previous
//
#include <hip/hip_runtime.h>
#include <math.h>

#define NQ 10
#define NL 4

typedef float v2f __attribute__((ext_vector_type(2)));

// ---------- cross-lane primitives (all R8/R10-verified) ----------
template<int CTRL>
__device__ __forceinline__ float dppx(float v) {  // DPP (VALU pipe)
  return __int_as_float(__builtin_amdgcn_update_dpp(0, __float_as_int(v), CTRL, 0xF, 0xF, true));
}
template<int OFF>
__device__ __forceinline__ float swzx(float v) {  // ds_swizzle (DS pipe)
  return __int_as_float(__builtin_amdgcn_ds_swizzle(__float_as_int(v), OFF));
}
__device__ __forceinline__ void pl16swap(float &a, float &b) {  // VALU
  asm("v_permlane16_swap_b32 %0, %1" : "+v"(a), "+v"(b));
}
__device__ __forceinline__ void pl32swap(float &a, float &b) {  // VALU
  asm("v_permlane32_swap_b32 %0, %1" : "+v"(a), "+v"(b));
}

// partner fetch for lane-bit LB in {0,1,2,3}: xor1/2 DPP (VALU), xor4/8 swizzle (DS)
template<int LB>
__device__ __forceinline__ float part(float v) {
  if constexpr (LB == 0) return dppx<0xB1>(v);
  else if constexpr (LB == 1) return dppx<0x4E>(v);
  else if constexpr (LB == 2) return swzx<0x101F>(v);
  else return swzx<0x201F>(v);
}

// ---------- packed complex arithmetic (VOP3P, R4-verified) ----------
__device__ __forceinline__ v2f cmul(v2f u, v2f a) {
  v2f d;
  asm("v_pk_mul_f32 %0, %1, %2 op_sel_hi:[0,1]\n\t"
      "v_pk_fma_f32 %0, %1, %2, %0 op_sel:[1,1,0] op_sel_hi:[1,0,1] neg_lo:[0,1,0]"
      : "=&v"(d) : "v"(u), "v"(a));
  return d;
}
__device__ __forceinline__ void cfma(v2f &d, v2f u, v2f a) {
  asm("v_pk_fma_f32 %0, %1, %2, %0 op_sel_hi:[0,1,1]\n\t"
      "v_pk_fma_f32 %0, %1, %2, %0 op_sel:[1,1,0] op_sel_hi:[1,0,1] neg_lo:[0,1,0]"
      : "+v"(d) : "v"(u), "v"(a));
}

// ---------- gates (R8-verified) ----------
template<int RB>
__device__ __forceinline__ void gate_rbit(v2f a[16], v2f u00, v2f u01, v2f u10, v2f u11) {
#pragma unroll
  for (int r0 = 0; r0 < 16; ++r0) {
    if ((r0 >> RB) & 1) continue;
    const int r1 = r0 | (1 << RB);
    const v2f a0 = a[r0], a1 = a[r1];
    v2f n0 = cmul(u00, a0); cfma(n0, u01, a1);
    v2f n1 = cmul(u10, a0); cfma(n1, u11, a1);
    a[r0] = n0;
    a[r1] = n1;
  }
}

template<int LB>
__device__ __forceinline__ void gate_part(v2f a[16], v2f cS, v2f cP) {
#pragma unroll
  for (int h = 0; h < 4; ++h) {
    v2f p[4];
#pragma unroll
    for (int k = 0; k < 4; ++k) {
      const int r = h * 4 + k;
      p[k].x = part<LB>(a[r].x);
      p[k].y = part<LB>(a[r].y);
    }
#pragma unroll
    for (int k = 0; k < 4; ++k) {
      const int r = h * 4 + k;
      v2f n = cmul(cS, a[r]); cfma(n, cP, p[k]);
      a[r] = n;
    }
  }
}

template<bool IS32>
__device__ __forceinline__ void gate_swap(v2f a[16], v2f cL, v2f cH) {
#pragma unroll
  for (int r = 0; r < 16; ++r) {
    float lx = a[r].x, hx = a[r].x;
    float ly = a[r].y, hy = a[r].y;
    if constexpr (IS32) { pl32swap(lx, hx); pl32swap(ly, hy); }
    else                { pl16swap(lx, hx); pl16swap(ly, hy); }
    v2f lo, hi;
    lo.x = lx; lo.y = ly;
    hi.x = hx; hi.y = hy;
    v2f n = cmul(cL, lo); cfma(n, cH, hi);
    a[r] = n;
  }
}

// ---------- CNOT ring as ONE linear permutation (HW-verified R2-R13):
// dst[r'][lane'] = src[gray4(r') ^ ((lane'&1)*12)][(lane'^(lane'>>1)) ^ ((r'&1)<<5)]
__device__ __forceinline__ void ring_comp(v2f a[16], int addr0, int addr1, bool odd) {
  float B[16];
#pragma unroll
  for (int g = 0; g < 16; ++g) {
    const int par = ((g ^ (g >> 1) ^ (g >> 2) ^ (g >> 3)) & 1);
    B[g] = __int_as_float(__builtin_amdgcn_ds_bpermute(par ? addr1 : addr0,
                                                       __float_as_int(a[g].x)));
  }
#pragma unroll
  for (int r = 0; r < 16; ++r) {
    const int g = (r ^ (r >> 1));
    a[r].x = odd ? B[g ^ 12] : B[g];
  }
#pragma unroll
  for (int g = 0; g < 16; ++g) {
    const int par = ((g ^ (g >> 1) ^ (g >> 2) ^ (g >> 3)) & 1);
    B[g] = __int_as_float(__builtin_amdgcn_ds_bpermute(par ? addr1 : addr0,
                                                       __float_as_int(a[g].y)));
  }
#pragma unroll
  for (int r = 0; r < 16; ++r) {
    const int g = (r ^ (r >> 1));
    a[r].y = odd ? B[g ^ 12] : B[g];
  }
}

// full 64-lane sum (R8-verified)
__device__ __forceinline__ float wsum(float v) {
  v += dppx<0xB1>(v);
  v += dppx<0x4E>(v);
  v += swzx<0x101F>(v);
  v += swzx<0x201F>(v);
  { float a = v, b = v; pl16swap(a, b); v = a + b; }
  { float a = v, b = v; pl32swap(a, b); v = a + b; }
  return v;
}

// product-state encoding (R4-verified structure; native trig verified in R10)
__device__ __forceinline__ void encode(const float* __restrict__ xb, int lane, v2f a[16]) {
  float lfac;
  {
    float c, s, h;
    h = 0.5f * xb[9]; s = __sinf(h); c = __cosf(h); lfac  = ((lane >> 0) & 1) ? s : c;
    h = 0.5f * xb[8]; s = __sinf(h); c = __cosf(h); lfac *= ((lane >> 1) & 1) ? s : c;
    h = 0.5f * xb[7]; s = __sinf(h); c = __cosf(h); lfac *= ((lane >> 2) & 1) ? s : c;
    h = 0.5f * xb[6]; s = __sinf(h); c = __cosf(h); lfac *= ((lane >> 3) & 1) ? s : c;
    h = 0.5f * xb[5]; s = __sinf(h); c = __cosf(h); lfac *= ((lane >> 4) & 1) ? s : c;
    h = 0.5f * xb[4]; s = __sinf(h); c = __cosf(h); lfac *= ((lane >> 5) & 1) ? s : c;
  }
  const float h0 = 0.5f * xb[0], h1 = 0.5f * xb[1], h2 = 0.5f * xb[2], h3 = 0.5f * xb[3];
  const float s0 = __sinf(h0), c0 = __cosf(h0);
  const float s1 = __sinf(h1), c1 = __cosf(h1);
  const float s2 = __sinf(h2), c2 = __cosf(h2);
  const float s3 = __sinf(h3), c3 = __cosf(h3);
#pragma unroll
  for (int r = 0; r < 16; ++r) {
    float f = lfac;                     // r bit rb <-> qubit 3-rb
    f *= ((r >> 0) & 1) ? s3 : c3;
    f *= ((r >> 1) & 1) ? s2 : c2;
    f *= ((r >> 2) & 1) ? s1 : c1;
    f *= ((r >> 3) & 1) ? s0 : c0;
    a[r].x = f;
    a[r].y = 0.f;
  }
}

__global__ __launch_bounds__(256) void qsim_kernel(const float* __restrict__ x,
                                                   const float* __restrict__ w,
                                                   float* __restrict__ out,
                                                   int batch) {
  // ---- per-block: the 40 Rot matrices into LDS (native trig, verified R10)
  __shared__ __align__(16) float gsh[NL * NQ * 8];
  const int tid = threadIdx.x;
  if (tid < NL * NQ) {
    const float phi = w[tid * 3 + 0];
    const float th  = w[tid * 3 + 1];
    const float om  = w[tid * 3 + 2];
    const float c  = __cosf(0.5f * th),          s  = __sinf(0.5f * th);
    const float cp = __cosf(-0.5f * (phi + om)), sp = __sinf(-0.5f * (phi + om));
    const float cm = __cosf(0.5f * (phi - om)),  sm = __sinf(0.5f * (phi - om));
    float* g = &gsh[tid * 8];
    g[0] = cp * c;  g[1] = sp * c;    // u00
    g[2] = -cm * s; g[3] = -sm * s;   // u01
    g[4] = cm * s;  g[5] = -sm * s;   // u10
    g[6] = cp * c;  g[7] = -sp * c;   // u11
  }
  __syncthreads();

  const int samp = (int)(blockIdx.x * (blockDim.x >> 6)) + (tid >> 6);
  const int lane = tid & 63;
  if (samp >= batch) return;

  const int addr0 = 4 * (lane ^ (lane >> 1));
  const int addr1 = addr0 ^ 128;
  const bool lodd = (lane & 1);

  v2f a[16];
  encode(x + samp * NQ, lane, a);

  // ---- layers (R8-verified bodies)
#pragma unroll
  for (int l = 0; l < NL; ++l) {
    const float* gl = &gsh[l * NQ * 8];

    // qubits 0..3: register-bit gates
#pragma unroll
    for (int q = 0; q < 4; ++q) {
      const v2f* gv = (const v2f*)(gl + q * 8);
      const v2f u00 = gv[0], u01 = gv[1], u10 = gv[2], u11 = gv[3];
      if (q == 0)      gate_rbit<3>(a, u00, u01, u10, u11);
      else if (q == 1) gate_rbit<2>(a, u00, u01, u10, u11);
      else if (q == 2) gate_rbit<1>(a, u00, u01, u10, u11);
      else             gate_rbit<0>(a, u00, u01, u10, u11);
    }
    // qubit 4 (lane bit 5): permlane32_swap gate (VALU)
    {
      const v2f* gv = (const v2f*)(gl + 4 * 8);
      const bool hb = (lane >> 5) & 1;
      gate_swap<true>(a, hb ? gv[2] : gv[0], hb ? gv[3] : gv[1]);
    }
    // qubit 5 (lane bit 4): permlane16_swap gate (VALU)
    {
      const v2f* gv = (const v2f*)(gl + 5 * 8);
      const bool hb = (lane >> 4) & 1;
      gate_swap<false>(a, hb ? gv[2] : gv[0], hb ? gv[3] : gv[1]);
    }
    // qubits 6..9 (lane bits 3..0): partner gates
#pragma unroll
    for (int q = 6; q < 10; ++q) {
      const v2f* gv = (const v2f*)(gl + q * 8);
      const bool hb = (lane >> (9 - q)) & 1;
      const v2f cS = hb ? gv[3] : gv[0];
      const v2f cP = hb ? gv[2] : gv[1];
      if (q == 6)      gate_part<3>(a, cS, cP);
      else if (q == 7) gate_part<2>(a, cS, cP);
      else if (q == 8) gate_part<1>(a, cS, cP);
      else             gate_part<0>(a, cS, cP);
    }

    // entire CNOT ring as one permutation
    ring_comp(a, addr0, addr1, lodd);
  }

  // ---- measurement (z0..3: signed partials + wsum; z4..9: WH butterfly — both R10-verified)
  float p[16];
#pragma unroll
  for (int r = 0; r < 16; ++r) p[r] = a[r].x * a[r].x + a[r].y * a[r].y;

  float z03[4];
#pragma unroll
  for (int q = 0; q < 4; ++q) {
    const int rb = 3 - q;
    float acc = 0.f;
#pragma unroll
    for (int r = 0; r < 16; ++r) acc += ((r >> rb) & 1) ? -p[r] : p[r];
    z03[q] = wsum(acc);
  }

  float P = 0.f;
#pragma unroll
  for (int r = 0; r < 16; ++r) P += p[r];
  const float sg0 = (lane & 1)  ? -1.f : 1.f;
  const float sg1 = (lane & 2)  ? -1.f : 1.f;
  const float sg2 = (lane & 4)  ? -1.f : 1.f;
  const float sg3 = (lane & 8)  ? -1.f : 1.f;
  const float sg4 = (lane & 16) ? -1.f : 1.f;
  const float sg5 = (lane & 32) ? -1.f : 1.f;
  float v = P;
  v = __builtin_fmaf(sg0, v, dppx<0xB1>(v));    // bit0
  v = __builtin_fmaf(sg1, v, dppx<0x4E>(v));    // bit1
  v = __builtin_fmaf(sg2, v, swzx<0x101F>(v));  // bit2 (DS)
  v = __builtin_fmaf(sg3, v, swzx<0x201F>(v));  // bit3 (DS)
  { float xx = v, yy = v; pl16swap(xx, yy); v = __builtin_fmaf(sg4, yy, xx); }  // bit4
  { float xx = v, yy = v; pl32swap(xx, yy); v = __builtin_fmaf(sg5, yy, xx); }  // bit5

  if (lane == 0) {
    out[samp * NQ + 0] = z03[0];
    out[samp * NQ + 1] = z03[1];
    out[samp * NQ + 2] = z03[2];
    out[samp * NQ + 3] = z03[3];
  } else if ((lane & (lane - 1)) == 0) {      // lane in {1,2,4,8,16,32}
    const int lb = __ffs(lane) - 1;           // 0..5
    out[samp * NQ + (9 - lb)] = v;            // q = 9 - lb in 4..9
  }
}

extern "C" void kernel_launch(void* const* d_in, const int* in_sizes, int n_in,
                              void* d_out, int out_size, void* d_ws, size_t ws_size,
                              hipStream_t stream) {
  const float* x = (const float*)d_in[0];
  const float* w = (const float*)d_in[1];
  float* out = (float*)d_out;
  const int batch = in_sizes[0] / NQ;
  const int waves_per_block = 256 / 64;
  const int grid = (batch + waves_per_block - 1) / waves_per_block;
  hipLaunchKernelGGL(qsim_kernel, dim3(grid), dim3(256), 0, stream, x, w, out, batch);
}

// Round 15
// 114.292 us; speedup vs baseline: 1.2893x; 1.1565x over previous
//
#include <hip/hip_runtime.h>
#include <math.h>

#define NQ 10
#define NL 4

typedef float v2f __attribute__((ext_vector_type(2)));

// ---------- cross-lane primitives (all R8/R10/R14-verified) ----------
template<int CTRL>
__device__ __forceinline__ float dppx(float v) {  // DPP (VALU pipe)
  return __int_as_float(__builtin_amdgcn_update_dpp(0, __float_as_int(v), CTRL, 0xF, 0xF, true));
}
template<int OFF>
__device__ __forceinline__ float swzx(float v) {  // ds_swizzle (DS pipe)
  return __int_as_float(__builtin_amdgcn_ds_swizzle(__float_as_int(v), OFF));
}
__device__ __forceinline__ void pl16swap(float &a, float &b) {  // VALU
  asm("v_permlane16_swap_b32 %0, %1" : "+v"(a), "+v"(b));
}
__device__ __forceinline__ void pl32swap(float &a, float &b) {  // VALU
  asm("v_permlane32_swap_b32 %0, %1" : "+v"(a), "+v"(b));
}

// partner fetch for lane-bit LB in {0,1,2,3}: xor1/2 DPP (VALU), xor4/8 swizzle (DS)
template<int LB>
__device__ __forceinline__ float part(float v) {
  if constexpr (LB == 0) return dppx<0xB1>(v);
  else if constexpr (LB == 1) return dppx<0x4E>(v);
  else if constexpr (LB == 2) return swzx<0x101F>(v);
  else return swzx<0x201F>(v);
}

// ---------- packed complex arithmetic (VOP3P, R4-verified) ----------
__device__ __forceinline__ v2f cmul(v2f u, v2f a) {
  v2f d;
  asm("v_pk_mul_f32 %0, %1, %2 op_sel_hi:[0,1]\n\t"
      "v_pk_fma_f32 %0, %1, %2, %0 op_sel:[1,1,0] op_sel_hi:[1,0,1] neg_lo:[0,1,0]"
      : "=&v"(d) : "v"(u), "v"(a));
  return d;
}
__device__ __forceinline__ void cfma(v2f &d, v2f u, v2f a) {
  asm("v_pk_fma_f32 %0, %1, %2, %0 op_sel_hi:[0,1,1]\n\t"
      "v_pk_fma_f32 %0, %1, %2, %0 op_sel:[1,1,0] op_sel_hi:[1,0,1] neg_lo:[0,1,0]"
      : "+v"(d) : "v"(u), "v"(a));
}

// ---------- gates (R8/R14-verified) ----------
template<int RB>
__device__ __forceinline__ void gate_rbit(v2f a[16], v2f u00, v2f u01, v2f u10, v2f u11) {
#pragma unroll
  for (int r0 = 0; r0 < 16; ++r0) {
    if ((r0 >> RB) & 1) continue;
    const int r1 = r0 | (1 << RB);
    const v2f a0 = a[r0], a1 = a[r1];
    v2f n0 = cmul(u00, a0); cfma(n0, u01, a1);
    v2f n1 = cmul(u10, a0); cfma(n1, u11, a1);
    a[r0] = n0;
    a[r1] = n1;
  }
}

template<int LB>
__device__ __forceinline__ void gate_part(v2f a[16], v2f cS, v2f cP) {
#pragma unroll
  for (int h = 0; h < 4; ++h) {
    v2f p[4];
#pragma unroll
    for (int k = 0; k < 4; ++k) {
      const int r = h * 4 + k;
      p[k].x = part<LB>(a[r].x);
      p[k].y = part<LB>(a[r].y);
    }
#pragma unroll
    for (int k = 0; k < 4; ++k) {
      const int r = h * 4 + k;
      v2f n = cmul(cS, a[r]); cfma(n, cP, p[k]);
      a[r] = n;
    }
  }
}

template<bool IS32>
__device__ __forceinline__ void gate_swap(v2f a[16], v2f cL, v2f cH) {
#pragma unroll
  for (int r = 0; r < 16; ++r) {
    float lx = a[r].x, hx = a[r].x;
    float ly = a[r].y, hy = a[r].y;
    if constexpr (IS32) { pl32swap(lx, hx); pl32swap(ly, hy); }
    else                { pl16swap(lx, hx); pl16swap(ly, hy); }
    v2f lo, hi;
    lo.x = lx; lo.y = ly;
    hi.x = hx; hi.y = hy;
    v2f n = cmul(cL, lo); cfma(n, cH, hi);
    a[r] = n;
  }
}

// ---------- CNOT ring as ONE linear permutation (HW-verified R2-R14):
// dst[r'][lane'] = src[gray4(r') ^ ((lane'&1)*12)][(lane'^(lane'>>1)) ^ ((r'&1)<<5)]
__device__ __forceinline__ void ring_comp(v2f a[16], int addr0, int addr1, bool odd) {
  float B[16];
#pragma unroll
  for (int g = 0; g < 16; ++g) {
    const int par = ((g ^ (g >> 1) ^ (g >> 2) ^ (g >> 3)) & 1);
    B[g] = __int_as_float(__builtin_amdgcn_ds_bpermute(par ? addr1 : addr0,
                                                       __float_as_int(a[g].x)));
  }
#pragma unroll
  for (int r = 0; r < 16; ++r) {
    const int g = (r ^ (r >> 1));
    a[r].x = odd ? B[g ^ 12] : B[g];
  }
#pragma unroll
  for (int g = 0; g < 16; ++g) {
    const int par = ((g ^ (g >> 1) ^ (g >> 2) ^ (g >> 3)) & 1);
    B[g] = __int_as_float(__builtin_amdgcn_ds_bpermute(par ? addr1 : addr0,
                                                       __float_as_int(a[g].y)));
  }
#pragma unroll
  for (int r = 0; r < 16; ++r) {
    const int g = (r ^ (r >> 1));
    a[r].y = odd ? B[g ^ 12] : B[g];
  }
}

// full 64-lane sum (R8-verified)
__device__ __forceinline__ float wsum(float v) {
  v += dppx<0xB1>(v);
  v += dppx<0x4E>(v);
  v += swzx<0x101F>(v);
  v += swzx<0x201F>(v);
  { float a = v, b = v; pl16swap(a, b); v = a + b; }
  { float a = v, b = v; pl32swap(a, b); v = a + b; }
  return v;
}

// product-state encoding (R14-verified)
__device__ __forceinline__ void encode(const float* __restrict__ xb, int lane, v2f a[16]) {
  float lfac;
  {
    float c, s, h;
    h = 0.5f * xb[9]; s = __sinf(h); c = __cosf(h); lfac  = ((lane >> 0) & 1) ? s : c;
    h = 0.5f * xb[8]; s = __sinf(h); c = __cosf(h); lfac *= ((lane >> 1) & 1) ? s : c;
    h = 0.5f * xb[7]; s = __sinf(h); c = __cosf(h); lfac *= ((lane >> 2) & 1) ? s : c;
    h = 0.5f * xb[6]; s = __sinf(h); c = __cosf(h); lfac *= ((lane >> 3) & 1) ? s : c;
    h = 0.5f * xb[5]; s = __sinf(h); c = __cosf(h); lfac *= ((lane >> 4) & 1) ? s : c;
    h = 0.5f * xb[4]; s = __sinf(h); c = __cosf(h); lfac *= ((lane >> 5) & 1) ? s : c;
  }
  const float h0 = 0.5f * xb[0], h1 = 0.5f * xb[1], h2 = 0.5f * xb[2], h3 = 0.5f * xb[3];
  const float s0 = __sinf(h0), c0 = __cosf(h0);
  const float s1 = __sinf(h1), c1 = __cosf(h1);
  const float s2 = __sinf(h2), c2 = __cosf(h2);
  const float s3 = __sinf(h3), c3 = __cosf(h3);
#pragma unroll
  for (int r = 0; r < 16; ++r) {
    float f = lfac;                     // r bit rb <-> qubit 3-rb
    f *= ((r >> 0) & 1) ? s3 : c3;
    f *= ((r >> 1) & 1) ? s2 : c2;
    f *= ((r >> 2) & 1) ? s1 : c1;
    f *= ((r >> 3) & 1) ? s0 : c0;
    a[r].x = f;
    a[r].y = 0.f;
  }
}

__global__ __launch_bounds__(256) void qsim_kernel(const float* __restrict__ x,
                                                   const float* __restrict__ w,
                                                   float* __restrict__ out,
                                                   int batch) {
  // ---- per-block: the 40 Rot matrices into LDS (R14-verified)
  __shared__ __align__(16) float gsh[NL * NQ * 8];
  const int tid = threadIdx.x;
  if (tid < NL * NQ) {
    const float phi = w[tid * 3 + 0];
    const float th  = w[tid * 3 + 1];
    const float om  = w[tid * 3 + 2];
    const float c  = __cosf(0.5f * th),          s  = __sinf(0.5f * th);
    const float cp = __cosf(-0.5f * (phi + om)), sp = __sinf(-0.5f * (phi + om));
    const float cm = __cosf(0.5f * (phi - om)),  sm = __sinf(0.5f * (phi - om));
    float* g = &gsh[tid * 8];
    g[0] = cp * c;  g[1] = sp * c;    // u00
    g[2] = -cm * s; g[3] = -sm * s;   // u01
    g[4] = cm * s;  g[5] = -sm * s;   // u10
    g[6] = cp * c;  g[7] = -sp * c;   // u11
  }
  __syncthreads();

  const int samp = (int)(blockIdx.x * (blockDim.x >> 6)) + (tid >> 6);
  const int lane = tid & 63;
  if (samp >= batch) return;

  const int addr0 = 4 * (lane ^ (lane >> 1));
  const int addr1 = addr0 ^ 128;
  const bool lodd = (lane & 1);

  v2f a[16];
  encode(x + samp * NQ, lane, a);

  // ---- layers (R14-verified bodies); the FINAL ring is folded into measurement
#pragma unroll
  for (int l = 0; l < NL; ++l) {
    const float* gl = &gsh[l * NQ * 8];

#pragma unroll
    for (int q = 0; q < 4; ++q) {
      const v2f* gv = (const v2f*)(gl + q * 8);
      const v2f u00 = gv[0], u01 = gv[1], u10 = gv[2], u11 = gv[3];
      if (q == 0)      gate_rbit<3>(a, u00, u01, u10, u11);
      else if (q == 1) gate_rbit<2>(a, u00, u01, u10, u11);
      else if (q == 2) gate_rbit<1>(a, u00, u01, u10, u11);
      else             gate_rbit<0>(a, u00, u01, u10, u11);
    }
    {
      const v2f* gv = (const v2f*)(gl + 4 * 8);
      const bool hb = (lane >> 5) & 1;
      gate_swap<true>(a, hb ? gv[2] : gv[0], hb ? gv[3] : gv[1]);
    }
    {
      const v2f* gv = (const v2f*)(gl + 5 * 8);
      const bool hb = (lane >> 4) & 1;
      gate_swap<false>(a, hb ? gv[2] : gv[0], hb ? gv[3] : gv[1]);
    }
#pragma unroll
    for (int q = 6; q < 10; ++q) {
      const v2f* gv = (const v2f*)(gl + q * 8);
      const bool hb = (lane >> (9 - q)) & 1;
      const v2f cS = hb ? gv[3] : gv[0];
      const v2f cP = hb ? gv[2] : gv[1];
      if (q == 6)      gate_part<3>(a, cS, cP);
      else if (q == 7) gate_part<2>(a, cS, cP);
      else if (q == 8) gate_part<1>(a, cS, cP);
      else             gate_part<0>(a, cS, cP);
    }

    if (l < NL - 1) ring_comp(a, addr0, addr1, lodd);   // final ring folded below
  }

  // ---- measurement with final-ring folded sign masks.
  // Derived by solving J = A·I from the verified ring formula (two independent
  // derivations agree): I9=J0..J8 -> q0:(r7,L63); I8=J8+J9 -> q1:(12,0);
  // I7 -> q2:(14,0); I6 -> q3:(15,0); I5..I0 -> q4..9:(15, L=32,48,56,60,62,63).
  float p[16];
#pragma unroll
  for (int r = 0; r < 16; ++r) p[r] = a[r].x * a[r].x + a[r].y * a[r].y;

  float S7 = 0.f, S12 = 0.f, S14 = 0.f, S15 = 0.f;
#pragma unroll
  for (int r = 0; r < 16; ++r) {
    const float pr = p[r];
    S7  += (__builtin_popcount(r & 7)  & 1) ? -pr : pr;
    S12 += (__builtin_popcount(r & 12) & 1) ? -pr : pr;
    S14 += (__builtin_popcount(r & 14) & 1) ? -pr : pr;
    S15 += (__builtin_popcount(r & 15) & 1) ? -pr : pr;
  }

  const float z0 = wsum((__popc(lane) & 1) ? -S7 : S7);  // lane-mask 63 = lane parity
  const float z1 = wsum(S12);
  const float z2 = wsum(S14);

  // signed WH butterfly on S15 (R14-verified stages): lane L holds
  // sum_{l'} (-1)^{parity(L & l')} S15[l'] -> read qubit with lane-mask Lm at lane Lm.
  const float sg0 = (lane & 1)  ? -1.f : 1.f;
  const float sg1 = (lane & 2)  ? -1.f : 1.f;
  const float sg2 = (lane & 4)  ? -1.f : 1.f;
  const float sg3 = (lane & 8)  ? -1.f : 1.f;
  const float sg4 = (lane & 16) ? -1.f : 1.f;
  const float sg5 = (lane & 32) ? -1.f : 1.f;
  float v = S15;
  v = __builtin_fmaf(sg0, v, dppx<0xB1>(v));
  v = __builtin_fmaf(sg1, v, dppx<0x4E>(v));
  v = __builtin_fmaf(sg2, v, swzx<0x101F>(v));
  v = __builtin_fmaf(sg3, v, swzx<0x201F>(v));
  { float xx = v, yy = v; pl16swap(xx, yy); v = __builtin_fmaf(sg4, yy, xx); }
  { float xx = v, yy = v; pl32swap(xx, yy); v = __builtin_fmaf(sg5, yy, xx); }

  if (lane == 0) {
    out[samp * NQ + 0] = z0;
    out[samp * NQ + 1] = z1;
    out[samp * NQ + 2] = z2;
    out[samp * NQ + 3] = v;              // z3: lane-mask 0
  } else if (lane == 32) out[samp * NQ + 4] = v;
  else if (lane == 48)   out[samp * NQ + 5] = v;
  else if (lane == 56)   out[samp * NQ + 6] = v;
  else if (lane == 60)   out[samp * NQ + 7] = v;
  else if (lane == 62)   out[samp * NQ + 8] = v;
  else if (lane == 63)   out[samp * NQ + 9] = v;
}

extern "C" void kernel_launch(void* const* d_in, const int* in_sizes, int n_in,
                              void* d_out, int out_size, void* d_ws, size_t ws_size,
                              hipStream_t stream) {
  const float* x = (const float*)d_in[0];
  const float* w = (const float*)d_in[1];
  float* out = (float*)d_out;
  const int batch = in_sizes[0] / NQ;
  const int waves_per_block = 256 / 64;
  const int grid = (batch + waves_per_block - 1) / waves_per_block;
  hipLaunchKernelGGL(qsim_kernel, dim3(grid), dim3(256), 0, stream, x, w, out, batch);
}